// Round 5
// baseline (987.525 us; speedup 1.0000x reference)
//
#include <hip/hip_runtime.h>

#define N_TOK  65536
#define N_CODE 8192
#define DIM    256

typedef _Float16 f16;
typedef _Float16 f16x8 __attribute__((ext_vector_type(8)));
typedef float    f32x4 __attribute__((ext_vector_type(4)));

// ---------- kernel 1: row sum-of-squares (one wave per row) ----------
__global__ __launch_bounds__(256) void rowsq_kernel(const float* __restrict__ src,
                                                    float* __restrict__ dst, int nrows) {
    int row  = blockIdx.x * 4 + (threadIdx.x >> 6);
    int lane = threadIdx.x & 63;
    if (row >= nrows) return;
    float4 v = ((const float4*)(src + (size_t)row * DIM))[lane];
    float s = v.x * v.x + v.y * v.y + v.z * v.z + v.w * v.w;
#pragma unroll
    for (int off = 32; off; off >>= 1) s += __shfl_down(s, off, 64);
    if (lane == 0) dst[row] = s;
}

// ---------- kernel 2: split W into 2 fp16 limbs (pre-scaled, subnormal-free) ----------
__global__ __launch_bounds__(256) void splitw_kernel(const float* __restrict__ W,
                                                     f16* __restrict__ W1,
                                                     f16* __restrict__ W2) {
    int f = blockIdx.x * 256 + threadIdx.x;          // float4 id
    float4 v = ((const float4*)W)[f];
    union { f16 h[4]; uint2 u; } p1, p2;
    float e[4] = {v.x, v.y, v.z, v.w};
#pragma unroll
    for (int i = 0; i < 4; ++i) {
        float ws = e[i] * 16384.0f;                  // exact (pow2)
        f16 w1 = (f16)ws;                            // RNE
        float r = (ws - (float)w1) * 2048.0f;        // exact
        p1.h[i] = w1; p2.h[i] = (f16)r;
    }
    ((uint2*)W1)[f] = p1.u;
    ((uint2*)W2)[f] = p2.u;
}

// ---------- kernel 3: fused MFMA GEMM + argmin, v3 ----------
// 256 blocks x 512 thr (8 waves, 2/SIMD). Wave owns 32 tokens; A-frags (both
// limbs, full K=256) persistent in 128 VGPRs. B streamed via 2x64KB LDS
// double-buffer (64 codes per barrier-pair, processed as two 32-code halves),
// global_load_lds(16) with XOR-permuted per-lane addresses.
// 2 accumulators per tile (main, merged-cross); B-frags reg-double-buffered.
__global__ __launch_bounds__(512, 2) void argmin_mfma3(
    const float* __restrict__ X, const f16* __restrict__ W1, const f16* __restrict__ W2,
    const float* __restrict__ sxq, const float* __restrict__ esq,
    int* __restrict__ out_idx) {

    __shared__ char wbuf[131072];   // [sel:2][limb:2][32KB = 64 codes x 512B]

    const int tid  = threadIdx.x;
    const int lane = tid & 63;
    const int wv   = tid >> 6;        // 0..7
    const int cl   = lane & 15;       // code-col within 16
    const int q    = lane >> 4;       // 0..3 k-octet
    const int cl7  = cl & 7;
    const int wavetok0 = blockIdx.x * 256 + wv * 32;

    // ---- A: 32 tokens x 256 dims -> 2 f16 limbs, persistent in regs ----
    // frag (mt, s): lane holds X[wavetok0 + mt*16 + cl][s*32 + q*8 + j]
    f16x8 a1[2][8], a2[2][8];
#pragma unroll
    for (int mt = 0; mt < 2; ++mt)
#pragma unroll
        for (int s = 0; s < 8; ++s) {
            const float* p = X + (size_t)(wavetok0 + mt * 16 + cl) * DIM + s * 32 + q * 8;
            float4 v0 = ((const float4*)p)[0];
            float4 v1 = ((const float4*)p)[1];
            float e[8] = {v0.x, v0.y, v0.z, v0.w, v1.x, v1.y, v1.z, v1.w};
#pragma unroll
            for (int j = 0; j < 8; ++j) {
                f16 h = (f16)e[j];
                float r = (e[j] - (float)h) * 2048.0f;   // exact
                a1[mt][s][j] = h;
                a2[mt][s][j] = (f16)r;
            }
        }

    float sxr[8];
#pragma unroll
    for (int mt = 0; mt < 2; ++mt)
#pragma unroll
        for (int r = 0; r < 4; ++r)
            sxr[mt * 4 + r] = sxq[wavetok0 + mt * 16 + q * 4 + r];

    float bestd[8];
    int   besti[8];
#pragma unroll
    for (int i = 0; i < 8; ++i) { bestd[i] = 3.4e38f; besti[i] = 0x7fffffff; }

    // ---- staging: 64 KB per ct (2 limbs x 64 codes x 512B), 64 DMA instrs, 8/wave.
    // instr (L, cp): lane i -> code c = 2cp + (i>>5), octet o = (i&31) ^ (c&7)
    // -> LDS layout: addr(L, c, o) = L*32768 + c*512 + ((o ^ (c&7))*16)
    auto stage = [&](int ct2, int sel) {
#pragma unroll
        for (int t = 0; t < 8; ++t) {
            int fi = wv * 8 + t;          // 0..63
            int L  = fi >> 5;             // limb
            int cp = fi & 31;             // code pair
            int c  = 2 * cp + (lane >> 5);
            int o  = (lane & 31) ^ (c & 7);
            const f16* gsrc = (L ? W2 : W1) + (size_t)(ct2 * 64 + c) * DIM + o * 8;
            char* ldst = wbuf + sel * 65536 + L * 32768 + cp * 1024;
            __builtin_amdgcn_global_load_lds(
                (const __attribute__((address_space(1))) unsigned int*)gsrc,
                (__attribute__((address_space(3))) unsigned int*)ldst, 16, 0, 0);
        }
    };

    stage(0, 0);
    __syncthreads();

    for (int ct = 0; ct < N_CODE / 64; ++ct) {
        if (ct + 1 < N_CODE / 64) stage(ct + 1, (ct + 1) & 1);
        const char* base = wbuf + (ct & 1) * 65536;

#pragma unroll
        for (int h = 0; h < 2; ++h) {
            float se0 = esq[ct * 64 + h * 32 + cl];
            float se1 = esq[ct * 64 + h * 32 + 16 + cl];

            f32x4 mainA[4], crossA[4];   // tile t = mt*2 + nt2
#pragma unroll
            for (int t = 0; t < 4; ++t) {
                mainA[t]  = (f32x4){0.f, 0.f, 0.f, 0.f};
                crossA[t] = (f32x4){0.f, 0.f, 0.f, 0.f};
            }

            // B-frag register double buffer
            f16x8 fb1[2][2], fb2[2][2];
#pragma unroll
            for (int nt2 = 0; nt2 < 2; ++nt2) {
                int n   = h * 32 + nt2 * 16 + cl;
                int off = n * 512 + (((0 * 4 + q) ^ cl7) * 16);
                fb1[0][nt2] = *(const f16x8*)(base + off);
                fb2[0][nt2] = *(const f16x8*)(base + 32768 + off);
            }
#pragma unroll
            for (int s = 0; s < 8; ++s) {
                int cur = s & 1;
                if (s < 7) {
                    int nx = cur ^ 1;
#pragma unroll
                    for (int nt2 = 0; nt2 < 2; ++nt2) {
                        int n   = h * 32 + nt2 * 16 + cl;
                        int off = n * 512 + ((((s + 1) * 4 + q) ^ cl7) * 16);
                        fb1[nx][nt2] = *(const f16x8*)(base + off);
                        fb2[nx][nt2] = *(const f16x8*)(base + 32768 + off);
                    }
                }
#pragma unroll
                for (int mt = 0; mt < 2; ++mt)
#pragma unroll
                    for (int nt2 = 0; nt2 < 2; ++nt2) {
                        int t = mt * 2 + nt2;
                        mainA[t]  = __builtin_amdgcn_mfma_f32_16x16x32_f16(a1[mt][s], fb1[cur][nt2], mainA[t], 0, 0, 0);
                        crossA[t] = __builtin_amdgcn_mfma_f32_16x16x32_f16(a2[mt][s], fb1[cur][nt2], crossA[t], 0, 0, 0);
                        crossA[t] = __builtin_amdgcn_mfma_f32_16x16x32_f16(a1[mt][s], fb2[cur][nt2], crossA[t], 0, 0, 0);
                    }
            }

            // epilogue: d = fl(fl(sx+se) - 2*dot); dot*2^14 = main + 2^-11*cross
            // candidates ascend in code (nt2, h, ct ascending): strict < keeps lowest.
#pragma unroll
            for (int mt = 0; mt < 2; ++mt)
#pragma unroll
                for (int nt2 = 0; nt2 < 2; ++nt2)
#pragma unroll
                    for (int r = 0; r < 4; ++r) {
                        int t = mt * 2 + nt2;
                        float mc = fmaf(crossA[t][r], 4.8828125e-4f, mainA[t][r]);  // *2^-11
                        float t1 = sxr[mt * 4 + r] + (nt2 ? se1 : se0);
                        float d  = fmaf(-1.220703125e-4f, mc, t1);                  // -2^-13
                        int slot = mt * 4 + r;
                        if (d < bestd[slot]) {
                            bestd[slot] = d;
                            besti[slot] = ct * 64 + h * 32 + nt2 * 16 + cl;
                        }
                    }
        }
        __syncthreads();
    }

    // ---- cross-lane reduction over the 16 code-lanes (lex (d, idx) min) ----
#pragma unroll
    for (int slot = 0; slot < 8; ++slot) {
        float d = bestd[slot];
        int   i = besti[slot];
#pragma unroll
        for (int off = 1; off < 16; off <<= 1) {
            float od = __shfl_xor(d, off, 64);
            int   oi = __shfl_xor(i, off, 64);
            if (od < d || (od == d && oi < i)) { d = od; i = oi; }
        }
        if (cl == 0)
            out_idx[wavetok0 + (slot >> 2) * 16 + q * 4 + (slot & 3)] = i;
    }
}

// ---------- kernel 4: gather + straight-through output + loss partials ----------
__global__ __launch_bounds__(256) void finalize_kernel(
    const float* __restrict__ X, const float* __restrict__ W,
    const int* __restrict__ idx, float* __restrict__ outQ,
    float* __restrict__ outI, double* __restrict__ accum) {
    __shared__ double wsum[4];
    int wid  = threadIdx.x >> 6;
    int lane = threadIdx.x & 63;
    int token = blockIdx.x * 4 + wid;
    int id = idx[token];
    float4 x = ((const float4*)(X + (size_t)token * DIM))[lane];
    float4 qv = ((const float4*)(W + (size_t)id * DIM))[lane];
    float4 o;
    o.x = x.x + (qv.x - x.x);
    o.y = x.y + (qv.y - x.y);
    o.z = x.z + (qv.z - x.z);
    o.w = x.w + (qv.w - x.w);
    ((float4*)(outQ + (size_t)token * DIM))[lane] = o;
    float dx = x.x - qv.x, dy = x.y - qv.y, dz = x.z - qv.z, dw = x.w - qv.w;
    float s = dx * dx + dy * dy + dz * dz + dw * dw;
#pragma unroll
    for (int off = 32; off; off >>= 1) s += __shfl_down(s, off, 64);
    if (lane == 0) {
        outI[token] = (float)id;
        wsum[wid] = (double)s;
    }
    __syncthreads();
    if (threadIdx.x == 0) {
        double t = wsum[0] + wsum[1] + wsum[2] + wsum[3];
        atomicAdd(accum, t);
    }
}

// ---------- kernel 5: scalars ----------
__global__ void scalars_kernel(const double* __restrict__ accum, float* __restrict__ out) {
    double mse = *accum / (double)((size_t)N_TOK * DIM);
    float c = (float)mse;
    out[0] = c + 0.25f * c;
    out[1] = c;
    out[2] = c;
}

extern "C" void kernel_launch(void* const* d_in, const int* in_sizes, int n_in,
                              void* d_out, int out_size, void* d_ws, size_t ws_size,
                              hipStream_t stream) {
    const float* X = (const float*)d_in[0];   // (65536, 256)
    const float* W = (const float*)d_in[1];   // (8192, 256)

    float* outQ = (float*)d_out;
    float* outI = outQ + (size_t)N_TOK * DIM;
    float* outS = outI + N_TOK;

    char* ws = (char*)d_ws;
    double* accum = (double*)ws;                         // @0
    float* esq = (float*)(ws + 64);                      // 32 KB
    float* sxq = (float*)(ws + 64 + 32768);              // 256 KB
    int*   idx = (int*)(ws + 64 + 32768 + 262144);       // 256 KB
    f16*   W1  = (f16*)(ws + (1 << 20));                 // 4 MB
    f16*   W2  = (f16*)(ws + (1 << 20) + 4194304);       // 4 MB

    hipMemsetAsync(accum, 0, sizeof(double), stream);
    splitw_kernel<<<N_CODE * DIM / 4 / 256, 256, 0, stream>>>(W, W1, W2);
    rowsq_kernel<<<N_CODE / 4, 256, 0, stream>>>(W, esq, N_CODE);
    rowsq_kernel<<<N_TOK / 4, 256, 0, stream>>>(X, sxq, N_TOK);
    argmin_mfma3<<<N_TOK / 256, 512, 0, stream>>>(X, W1, W2, sxq, esq, idx);
    finalize_kernel<<<N_TOK / 4, 256, 0, stream>>>(X, W, idx, outQ, outI, accum);
    scalars_kernel<<<1, 1, 0, stream>>>(accum, outS);
}